// Round 1
// 514.150 us; speedup vs baseline: 1.0014x; 1.0014x over previous
//
#include <hip/hip_runtime.h>
#include <math.h>

#define B 4
#define C 256
#define T 8
#define H 128
#define WW 64
#define IC 128
#define S 64          // t*STRIPE tokens
#define NSTRIPE 8
#define HS 16
#define REGION 1024   // HS*WW contiguous floats per stripe region
#define EPS 1e-5f

// ---------------- K1: stripe mean pool ----------------
// One region (1024 floats) per WAVE: 4 float4 per lane, shfl reduce, no LDS.
// grid = B*C*T*NSTRIPE/4 = 16384 blocks, 256 threads (4 waves).
// Writes dn in (b, s, c) layout so proj's staging load is coalesced.
__global__ void pool_kernel(const float* __restrict__ x, float* __restrict__ dn) {
    int wid = threadIdx.x >> 6;
    int lane = threadIdx.x & 63;
    int sb = blockIdx.x * 4 + wid;            // flat (b,c,t,stripe) region index
    const float4* xr = (const float4*)(x + (size_t)sb * REGION);
    float sum = 0.0f;
    #pragma unroll
    for (int k = 0; k < 4; ++k) {
        float4 v = xr[k * 64 + lane];
        sum += v.x + v.y + v.z + v.w;
    }
    #pragma unroll
    for (int off = 32; off > 0; off >>= 1)
        sum += __shfl_down(sum, off, 64);
    if (lane == 0) {
        int b = sb >> 14;
        int c = (sb >> 6) & 255;
        int s = sb & 63;                       // s = t*8 + stripe
        dn[(((size_t)b << 6) | s) * C + c] = sum * (1.0f / (float)REGION);
    }
}

// ---------------- K2: g/theta/phi projections ----------------
// grid = B*S = 256 blocks, 384 threads: p = tid>>7 selects {g,theta,phi},
// i = tid&127 is the output channel. float4-vectorized 64-iter loop.
__global__ void proj_kernel(const float* __restrict__ dn,
                            const float* __restrict__ gw, const float* __restrict__ gb,
                            const float* __restrict__ tw, const float* __restrict__ tb,
                            const float* __restrict__ pw, const float* __restrict__ pb,
                            float* __restrict__ g, float* __restrict__ th,
                            float* __restrict__ ph) {
    int blk = blockIdx.x;                      // b*64 + s
    __shared__ float4 dloc[C / 4];
    int tid = threadIdx.x;
    if (tid < C / 4)
        dloc[tid] = ((const float4*)(dn + (size_t)blk * C))[tid];
    __syncthreads();
    int p = tid >> 7;                          // 0..2
    int i = tid & 127;
    const float* wsel = (p == 0) ? gw : (p == 1) ? tw : pw;
    const float* bsel = (p == 0) ? gb : (p == 1) ? tb : pb;
    float* osel      = (p == 0) ? g  : (p == 1) ? th : ph;
    const float4* wr = (const float4*)(wsel + (size_t)i * C);
    float4 a = {0.f, 0.f, 0.f, 0.f};
    #pragma unroll 8
    for (int k = 0; k < C / 4; ++k) {
        float4 wv = wr[k];
        float4 dv = dloc[k];
        a.x = fmaf(dv.x, wv.x, a.x);
        a.y = fmaf(dv.y, wv.y, a.y);
        a.z = fmaf(dv.z, wv.z, a.z);
        a.w = fmaf(dv.w, wv.w, a.w);
    }
    osel[(size_t)blk * IC + i] = a.x + a.y + a.z + a.w + bsel[i];
}

// ---------------- K3: attention + output projection + BN (fused) ----------------
// grid = B*S = 256 blocks, 256 threads.
// Phase 1: scores via 4-thread-split float4 dots (all 256 threads active).
// Phase 2: wave-0 softmax. Phase 3: y from LDS-staged g, split over r-halves.
// Phase 4: wy[ch] = BN(y . Ww[ch] + Wb[ch]) for ch = tid — coalesced write
// in (b, s, c) layout.
__global__ void attn_out_kernel(const float* __restrict__ g,
                                const float* __restrict__ th,
                                const float* __restrict__ ph,
                                const float* __restrict__ Ww, const float* __restrict__ Wb,
                                const float* __restrict__ gamma, const float* __restrict__ beta,
                                const float* __restrict__ mean, const float* __restrict__ var,
                                float* __restrict__ wy) {
    int blk = blockIdx.x;                      // b*64 + s
    int b = blk >> 6;
    int tid = threadIdx.x;

    __shared__ float thloc[IC];
    __shared__ float gloc[S][IC];              // 32 KiB
    __shared__ float sc[S];
    __shared__ float pvals[S];
    __shared__ float ypart[2][IC];
    __shared__ float yloc[IC];

    // stage th row (128 floats) + entire g block for this b (64x128)
    if (tid < IC) thloc[tid] = th[(size_t)blk * IC + tid];
    {
        const float4* gsrc = (const float4*)(g + (size_t)(b * S) * IC);
        float4* gdst = (float4*)&gloc[0][0];
        #pragma unroll
        for (int k = 0; k < (S * IC / 4) / 256; ++k)   // 8 iters
            gdst[k * 256 + tid] = gsrc[k * 256 + tid];
    }
    __syncthreads();

    // --- scores: thread (r = tid>>2, q = tid&3) does a 32-wide partial dot ---
    {
        int r = tid >> 2, q = tid & 3;
        const float4* phr = (const float4*)(ph + (size_t)(b * S + r) * IC) + q * 8;
        const float4* th4 = (const float4*)thloc + q * 8;
        float4 a = {0.f, 0.f, 0.f, 0.f};
        #pragma unroll
        for (int k = 0; k < 8; ++k) {
            float4 pv = phr[k];
            float4 tv = th4[k];
            a.x = fmaf(tv.x, pv.x, a.x);
            a.y = fmaf(tv.y, pv.y, a.y);
            a.z = fmaf(tv.z, pv.z, a.z);
            a.w = fmaf(tv.w, pv.w, a.w);
        }
        float f = a.x + a.y + a.z + a.w;
        f += __shfl_xor(f, 1, 64);
        f += __shfl_xor(f, 2, 64);             // all 4 lanes of the group have it
        if (q == 0) sc[r] = f;
    }
    __syncthreads();

    // --- softmax over the 64 scores, wave 0 ---
    if (tid < 64) {
        float v = sc[tid];
        float m = v;
        #pragma unroll
        for (int off = 32; off > 0; off >>= 1)
            m = fmaxf(m, __shfl_xor(m, off, 64));
        float e = __expf(v - m);
        float sum = e;
        #pragma unroll
        for (int off = 32; off > 0; off >>= 1)
            sum += __shfl_xor(sum, off, 64);
        pvals[tid] = e / sum;
    }
    __syncthreads();

    // --- y[i] = sum_r p[r] * g[r][i], split over r-halves ---
    {
        int i = tid & 127, half = tid >> 7;
        float acc = 0.0f;
        int r0 = half * 32;
        #pragma unroll 8
        for (int r = r0; r < r0 + 32; ++r)
            acc = fmaf(pvals[r], gloc[r][i], acc);
        ypart[half][i] = acc;
    }
    __syncthreads();
    if (tid < IC) yloc[tid] = ypart[0][tid] + ypart[1][tid];
    __syncthreads();

    // --- output projection + BatchNorm: thread = output channel ch ---
    {
        const float4* wr = (const float4*)(Ww + (size_t)tid * IC);
        const float4* y4 = (const float4*)yloc;
        float4 o = {0.f, 0.f, 0.f, 0.f};
        #pragma unroll 8
        for (int k = 0; k < IC / 4; ++k) {
            float4 wv = wr[k];
            float4 yv = y4[k];
            o.x = fmaf(yv.x, wv.x, o.x);
            o.y = fmaf(yv.y, wv.y, o.y);
            o.z = fmaf(yv.z, wv.z, o.z);
            o.w = fmaf(yv.w, wv.w, o.w);
        }
        float acc = o.x + o.y + o.z + o.w + Wb[tid];
        float inv = gamma[tid] * rsqrtf(var[tid] + EPS);
        // (b, s, c) layout: coalesced across tid
        wy[(size_t)blk * C + tid] = (acc - mean[tid]) * inv + beta[tid];
    }
}

// ---------------- K4: broadcast residual add ----------------
// One float4 per thread; 256 consecutive float4s share one wy value.
// wy is in (b, s, c) layout.
__global__ void add_kernel(const float* __restrict__ x,
                           const float* __restrict__ wy,
                           float* __restrict__ out) {
    size_t f = (size_t)blockIdx.x * blockDim.x + threadIdx.x;
    const float4* x4 = (const float4*)x;
    float4* o4 = (float4*)out;
    float4 v = x4[f];
    size_t rgn = f >> 8;                       // flat (b,c,t,stripe)
    int b = (int)(rgn >> 14);
    int c = (int)(rgn >> 6) & 255;
    int s = (int)rgn & 63;
    float a = wy[((((size_t)b << 6) | s) << 8) | c];
    v.x += a; v.y += a; v.z += a; v.w += a;
    o4[f] = v;
}

extern "C" void kernel_launch(void* const* d_in, const int* in_sizes, int n_in,
                              void* d_out, int out_size, void* d_ws, size_t ws_size,
                              hipStream_t stream) {
    const float* x       = (const float*)d_in[0];
    const float* g_w     = (const float*)d_in[1];
    const float* g_b     = (const float*)d_in[2];
    const float* theta_w = (const float*)d_in[3];
    const float* theta_b = (const float*)d_in[4];
    const float* phi_w   = (const float*)d_in[5];
    const float* phi_b   = (const float*)d_in[6];
    const float* W_w     = (const float*)d_in[7];
    const float* W_b     = (const float*)d_in[8];
    const float* bn_g    = (const float*)d_in[9];
    const float* bn_b    = (const float*)d_in[10];
    const float* bn_m    = (const float*)d_in[11];
    const float* bn_v    = (const float*)d_in[12];
    float* out = (float*)d_out;

    // workspace layout (floats)
    float* ws = (float*)d_ws;
    float* dn = ws;                  // B*S*C  = 65536  (b,s,c layout)
    float* g  = dn + B * C * S;      // B*S*IC = 32768
    float* th = g  + B * S * IC;     // 32768
    float* ph = th + B * S * IC;     // 32768
    float* wy = ph + B * S * IC;     // B*S*C  = 65536  (b,s,c layout)

    const int nRegions = B * C * T * NSTRIPE;              // 65536
    pool_kernel<<<nRegions / 4, 256, 0, stream>>>(x, dn);

    proj_kernel<<<B * S, 384, 0, stream>>>(dn, g_w, g_b, theta_w, theta_b,
                                           phi_w, phi_b, g, th, ph);

    attn_out_kernel<<<B * S, 256, 0, stream>>>(g, th, ph, W_w, W_b,
                                               bn_g, bn_b, bn_m, bn_v, wy);

    const size_t nVec4 = (size_t)B * C * T * H * WW / 4;   // 16777216
    add_kernel<<<(int)(nVec4 / 256), 256, 0, stream>>>(x, wy, out);
}

// Round 2
// 506.084 us; speedup vs baseline: 1.0173x; 1.0159x over previous
//
#include <hip/hip_runtime.h>
#include <math.h>

#define B 4
#define C 256
#define T 8
#define H 128
#define WW 64
#define IC 128
#define S 64          // t*STRIPE tokens
#define NSTRIPE 8
#define HS 16
#define REGION 1024   // HS*WW contiguous floats per stripe region
#define EPS 1e-5f

typedef float f32x4 __attribute__((ext_vector_type(4)));

// ---------------- K1: stripe mean pool ----------------
// One region (1024 floats) per WAVE: 4 float4 per lane, shfl reduce, no LDS.
// grid = B*C*T*NSTRIPE/4 = 16384 blocks, 256 threads (4 waves).
// Normal (cacheable) loads on purpose: they leave x resident in L3 so the
// add kernel's re-read is an L3 hit.
// Writes dn in (b, s, c) layout so proj's staging load is coalesced.
__global__ void pool_kernel(const float* __restrict__ x, float* __restrict__ dn) {
    int wid = threadIdx.x >> 6;
    int lane = threadIdx.x & 63;
    int sb = blockIdx.x * 4 + wid;            // flat (b,c,t,stripe) region index
    const float4* xr = (const float4*)(x + (size_t)sb * REGION);
    float sum = 0.0f;
    #pragma unroll
    for (int k = 0; k < 4; ++k) {
        float4 v = xr[k * 64 + lane];
        sum += v.x + v.y + v.z + v.w;
    }
    #pragma unroll
    for (int off = 32; off > 0; off >>= 1)
        sum += __shfl_down(sum, off, 64);
    if (lane == 0) {
        int b = sb >> 14;
        int c = (sb >> 6) & 255;
        int s = sb & 63;                       // s = t*8 + stripe
        dn[(((size_t)b << 6) | s) * C + c] = sum * (1.0f / (float)REGION);
    }
}

// ---------------- K2: g/theta/phi projections ----------------
// grid = B*S = 256 blocks, 384 threads: p = tid>>7 selects {g,theta,phi},
// i = tid&127 is the output channel. float4-vectorized 64-iter loop.
__global__ void proj_kernel(const float* __restrict__ dn,
                            const float* __restrict__ gw, const float* __restrict__ gb,
                            const float* __restrict__ tw, const float* __restrict__ tb,
                            const float* __restrict__ pw, const float* __restrict__ pb,
                            float* __restrict__ g, float* __restrict__ th,
                            float* __restrict__ ph) {
    int blk = blockIdx.x;                      // b*64 + s
    __shared__ float4 dloc[C / 4];
    int tid = threadIdx.x;
    if (tid < C / 4)
        dloc[tid] = ((const float4*)(dn + (size_t)blk * C))[tid];
    __syncthreads();
    int p = tid >> 7;                          // 0..2
    int i = tid & 127;
    const float* wsel = (p == 0) ? gw : (p == 1) ? tw : pw;
    const float* bsel = (p == 0) ? gb : (p == 1) ? tb : pb;
    float* osel      = (p == 0) ? g  : (p == 1) ? th : ph;
    const float4* wr = (const float4*)(wsel + (size_t)i * C);
    float4 a = {0.f, 0.f, 0.f, 0.f};
    #pragma unroll 8
    for (int k = 0; k < C / 4; ++k) {
        float4 wv = wr[k];
        float4 dv = dloc[k];
        a.x = fmaf(dv.x, wv.x, a.x);
        a.y = fmaf(dv.y, wv.y, a.y);
        a.z = fmaf(dv.z, wv.z, a.z);
        a.w = fmaf(dv.w, wv.w, a.w);
    }
    osel[(size_t)blk * IC + i] = a.x + a.y + a.z + a.w + bsel[i];
}

// ---------------- K3: attention + output projection + BN (fused) ----------------
// grid = B*S = 256 blocks, 256 threads. Same as round-1 (verified).
__global__ void attn_out_kernel(const float* __restrict__ g,
                                const float* __restrict__ th,
                                const float* __restrict__ ph,
                                const float* __restrict__ Ww, const float* __restrict__ Wb,
                                const float* __restrict__ gamma, const float* __restrict__ beta,
                                const float* __restrict__ mean, const float* __restrict__ var,
                                float* __restrict__ wy) {
    int blk = blockIdx.x;                      // b*64 + s
    int b = blk >> 6;
    int tid = threadIdx.x;

    __shared__ float thloc[IC];
    __shared__ float gloc[S][IC];              // 32 KiB
    __shared__ float sc[S];
    __shared__ float pvals[S];
    __shared__ float ypart[2][IC];
    __shared__ float yloc[IC];

    if (tid < IC) thloc[tid] = th[(size_t)blk * IC + tid];
    {
        const float4* gsrc = (const float4*)(g + (size_t)(b * S) * IC);
        float4* gdst = (float4*)&gloc[0][0];
        #pragma unroll
        for (int k = 0; k < (S * IC / 4) / 256; ++k)   // 8 iters
            gdst[k * 256 + tid] = gsrc[k * 256 + tid];
    }
    __syncthreads();

    // --- scores: thread (r = tid>>2, q = tid&3) does a 32-wide partial dot ---
    {
        int r = tid >> 2, q = tid & 3;
        const float4* phr = (const float4*)(ph + (size_t)(b * S + r) * IC) + q * 8;
        const float4* th4 = (const float4*)thloc + q * 8;
        float4 a = {0.f, 0.f, 0.f, 0.f};
        #pragma unroll
        for (int k = 0; k < 8; ++k) {
            float4 pv = phr[k];
            float4 tv = th4[k];
            a.x = fmaf(tv.x, pv.x, a.x);
            a.y = fmaf(tv.y, pv.y, a.y);
            a.z = fmaf(tv.z, pv.z, a.z);
            a.w = fmaf(tv.w, pv.w, a.w);
        }
        float f = a.x + a.y + a.z + a.w;
        f += __shfl_xor(f, 1, 64);
        f += __shfl_xor(f, 2, 64);
        if (q == 0) sc[r] = f;
    }
    __syncthreads();

    // --- softmax over the 64 scores, wave 0 ---
    if (tid < 64) {
        float v = sc[tid];
        float m = v;
        #pragma unroll
        for (int off = 32; off > 0; off >>= 1)
            m = fmaxf(m, __shfl_xor(m, off, 64));
        float e = __expf(v - m);
        float sum = e;
        #pragma unroll
        for (int off = 32; off > 0; off >>= 1)
            sum += __shfl_xor(sum, off, 64);
        pvals[tid] = e / sum;
    }
    __syncthreads();

    // --- y[i] = sum_r p[r] * g[r][i], split over r-halves ---
    {
        int i = tid & 127, half = tid >> 7;
        float acc = 0.0f;
        int r0 = half * 32;
        #pragma unroll 8
        for (int r = r0; r < r0 + 32; ++r)
            acc = fmaf(pvals[r], gloc[r][i], acc);
        ypart[half][i] = acc;
    }
    __syncthreads();
    if (tid < IC) yloc[tid] = ypart[0][tid] + ypart[1][tid];
    __syncthreads();

    // --- output projection + BatchNorm: thread = output channel ch ---
    {
        const float4* wr = (const float4*)(Ww + (size_t)tid * IC);
        const float4* y4 = (const float4*)yloc;
        float4 o = {0.f, 0.f, 0.f, 0.f};
        #pragma unroll 8
        for (int k = 0; k < IC / 4; ++k) {
            float4 wv = wr[k];
            float4 yv = y4[k];
            o.x = fmaf(yv.x, wv.x, o.x);
            o.y = fmaf(yv.y, wv.y, o.y);
            o.z = fmaf(yv.z, wv.z, o.z);
            o.w = fmaf(yv.w, wv.w, o.w);
        }
        float acc = o.x + o.y + o.z + o.w + Wb[tid];
        float inv = gamma[tid] * rsqrtf(var[tid] + EPS);
        wy[(size_t)blk * C + tid] = (acc - mean[tid]) * inv + beta[tid];
    }
}

// ---------------- K4: broadcast residual add ----------------
// 2 float4 per thread, block-contiguous (block covers exactly 2 regions).
// wy lookups are wave-uniform per 256-float4 chunk -> scalar loads.
// Non-temporal stores for out: do NOT allocate out lines in L2/L3, so the
// L3 stays holding x (exactly 256 MiB) and the x re-read is an L3 hit.
__global__ void add_kernel(const float* __restrict__ x,
                           const float* __restrict__ wy,
                           float* __restrict__ out) {
    int tid = threadIdx.x;
    size_t base = (size_t)blockIdx.x * 512;    // in float4 units
    int r0 = blockIdx.x * 2;                   // flat (b,c,t,stripe) region
    int r1 = r0 + 1;
    int b0 = r0 >> 14, c0 = (r0 >> 6) & 255, s0 = r0 & 63;
    int b1 = r1 >> 14, c1 = (r1 >> 6) & 255, s1 = r1 & 63;
    float a0 = wy[((((size_t)b0 << 6) | s0) << 8) | c0];
    float a1 = wy[((((size_t)b1 << 6) | s1) << 8) | c1];
    const f32x4* x4 = (const f32x4*)x;
    f32x4* o4 = (f32x4*)out;
    f32x4 v0 = x4[base + tid];
    f32x4 v1 = x4[base + 256 + tid];
    v0 += a0;
    v1 += a1;
    __builtin_nontemporal_store(v0, &o4[base + tid]);
    __builtin_nontemporal_store(v1, &o4[base + 256 + tid]);
}

extern "C" void kernel_launch(void* const* d_in, const int* in_sizes, int n_in,
                              void* d_out, int out_size, void* d_ws, size_t ws_size,
                              hipStream_t stream) {
    const float* x       = (const float*)d_in[0];
    const float* g_w     = (const float*)d_in[1];
    const float* g_b     = (const float*)d_in[2];
    const float* theta_w = (const float*)d_in[3];
    const float* theta_b = (const float*)d_in[4];
    const float* phi_w   = (const float*)d_in[5];
    const float* phi_b   = (const float*)d_in[6];
    const float* W_w     = (const float*)d_in[7];
    const float* W_b     = (const float*)d_in[8];
    const float* bn_g    = (const float*)d_in[9];
    const float* bn_b    = (const float*)d_in[10];
    const float* bn_m    = (const float*)d_in[11];
    const float* bn_v    = (const float*)d_in[12];
    float* out = (float*)d_out;

    // workspace layout (floats)
    float* ws = (float*)d_ws;
    float* dn = ws;                  // B*S*C  = 65536  (b,s,c layout)
    float* g  = dn + B * C * S;      // B*S*IC = 32768
    float* th = g  + B * S * IC;     // 32768
    float* ph = th + B * S * IC;     // 32768
    float* wy = ph + B * S * IC;     // B*S*C  = 65536  (b,s,c layout)

    const int nRegions = B * C * T * NSTRIPE;              // 65536
    pool_kernel<<<nRegions / 4, 256, 0, stream>>>(x, dn);

    proj_kernel<<<B * S, 384, 0, stream>>>(dn, g_w, g_b, theta_w, theta_b,
                                           phi_w, phi_b, g, th, ph);

    attn_out_kernel<<<B * S, 256, 0, stream>>>(g, th, ph, W_w, W_b,
                                               bn_g, bn_b, bn_m, bn_v, wy);

    const size_t nVec4 = (size_t)B * C * T * H * WW / 4;   // 16777216
    add_kernel<<<(int)(nVec4 / 512), 256, 0, stream>>>(x, wy, out);
}